// Round 5
// baseline (299.590 us; speedup 1.0000x reference)
//
#include <hip/hip_runtime.h>
#include <hip/hip_bf16.h>

typedef __bf16 bf16_t;
typedef __bf16 bf16x8 __attribute__((ext_vector_type(8)));
typedef float f32x4 __attribute__((ext_vector_type(4)));

#define HD 128
#define NN 384
#define ROWS 768           // B*N
#define SZ 98304           // ROWS*HD
#define JC 6               // j-chunks per (b,i)
// ws f32 layout: [0..4*SZ) = AhC, Bh, Vh, Uh ; [4*SZ ..) = agg partials [JC][ROWS][HD]

// ---- runtime input-dtype detector: 1 if buffer holds f32, 0 if bf16 ----
__device__ inline int detect_f32(const void* p) {
    const unsigned short* u = (const unsigned short*)p;
    int bad = 0;
    #pragma unroll
    for (int k = 0; k < 128; ++k) {
        int e = (u[k] >> 7) & 0xFF;
        bad += (e < 110 || e > 135) ? 1 : 0;
    }
    return bad >= 16 ? 1 : 0;
}

// ---- dtype-generic load helpers ----
__device__ inline void ld8(const float* p, float* o) {
    f32x4 a = *(const f32x4*)p;
    f32x4 b = *(const f32x4*)(p + 4);
    o[0] = a[0]; o[1] = a[1]; o[2] = a[2]; o[3] = a[3];
    o[4] = b[0]; o[5] = b[1]; o[6] = b[2]; o[7] = b[3];
}
__device__ inline void ld8(const bf16_t* p, float* o) {
    bf16x8 v = *(const bf16x8*)p;
    #pragma unroll
    for (int e = 0; e < 8; ++e) o[e] = (float)v[e];
}
__device__ inline bf16x8 ld8b(const float* p) {
    f32x4 a = *(const f32x4*)p;
    f32x4 b = *(const f32x4*)(p + 4);
    bf16x8 v;
    #pragma unroll
    for (int e = 0; e < 4; ++e) { v[e] = (bf16_t)a[e]; v[e + 4] = (bf16_t)b[e]; }
    return v;
}
__device__ inline bf16x8 ld8b(const bf16_t* p) { return *(const bf16x8*)p; }

// ---------------- Kernel 1: node linear layers ----------------
// grid (768, 4): row x matrix; block 128
template<typename T>
__device__ void node_body(float* x,
    const T* h_nodes, const T* Uw, const T* Ub, const T* Vw, const T* Vb,
    const T* Aw, const T* Ab, const T* Bw, const T* Bb, const T* Cb,
    float* ws)
{
    const int row = blockIdx.x, m = blockIdx.y, t = threadIdx.x;
    x[t] = (float)h_nodes[row * HD + t];
    __syncthreads();

    const T* Ws[4] = {Aw, Bw, Vw, Uw};
    float bias;
    if (m == 0)      bias = (float)Ab[t] + (float)Cb[t];
    else if (m == 1) bias = (float)Bb[t];
    else if (m == 2) bias = (float)Vb[t];
    else             bias = (float)Ub[t];

    float acc = bias;
    const T* W = Ws[m] + (size_t)t * HD;
    #pragma unroll
    for (int kk = 0; kk < 16; ++kk) {
        float w8[8];
        ld8(W + kk * 8, w8);
        #pragma unroll
        for (int e = 0; e < 8; ++e) acc = fmaf(x[kk * 8 + e], w8[e], acc);
    }
    ws[m * SZ + row * HD + t] = acc;
}

__global__ __launch_bounds__(128) void node_linear(
    const void* h_nodes, const void* Uw, const void* Ub, const void* Vw, const void* Vb,
    const void* Aw, const void* Ab, const void* Bw, const void* Bb, const void* Cb,
    float* __restrict__ ws)
{
    __shared__ __align__(16) float x[HD];
    if (detect_f32(h_nodes))
        node_body<float>(x, (const float*)h_nodes, (const float*)Uw, (const float*)Ub,
                         (const float*)Vw, (const float*)Vb, (const float*)Aw, (const float*)Ab,
                         (const float*)Bw, (const float*)Bb, (const float*)Cb, ws);
    else
        node_body<bf16_t>(x, (const bf16_t*)h_nodes, (const bf16_t*)Uw, (const bf16_t*)Ub,
                          (const bf16_t*)Vw, (const bf16_t*)Vb, (const bf16_t*)Aw, (const bf16_t*)Ab,
                          (const bf16_t*)Bw, (const bf16_t*)Bb, (const bf16_t*)Cb, ws);
}

// ---------------- Kernel 2: edge pipeline (one 16-row j-tile per wave) ----------------
// grid (384, JC, 2); block 256 = 4 waves
struct Smem {
    float sE[4][16][132];
    float sAhC[HD], sGe[HD], sBe[HD];
    float sAgg[4][HD];
};

template<typename T>
__device__ void edge_body(Smem& sm,
    const T* h_edges, const T* adj, const T* Cw,
    const T* ge, const T* be,
    const float* ws, float* wagg, float* out)
{
    const int i = blockIdx.x, jc = blockIdx.y, b = blockIdx.z;
    const int bi = b * NN + i;
    const int t = threadIdx.x;
    const int l = t & 63, w = t >> 6;
    const int lr = l & 15, lg = l >> 4;

    if (t < HD) {
        sm.sAhC[t] = ws[0 * SZ + bi * HD + t];
        sm.sGe[t]  = (float)ge[t];
        sm.sBe[t]  = (float)be[t];
    }

    // B-fragments: whole C_w per-wave in VGPRs; B[k][n] = Cw[n][k]; n = lr, k = ks*32+lg*8+e
    bf16x8 Bf[8][4];
    #pragma unroll
    for (int ct = 0; ct < 8; ++ct)
        #pragma unroll
        for (int ks = 0; ks < 4; ++ks)
            Bf[ct][ks] = ld8b(&Cw[(size_t)(ct * 16 + lr) * HD + ks * 32 + lg * 8]);

    const T* Ebase = h_edges + (size_t)bi * NN * HD;
    float* Obase = out + SZ + (size_t)bi * NN * HD;
    const float* BhB = ws + 1 * SZ + (size_t)b * NN * HD;
    const float* VhB = ws + 2 * SZ + (size_t)b * NN * HD;

    const int j0 = jc * 64 + w * 16;
    const int row = l >> 2, c = l & 3, h0 = c * 32;

    // ---- MFMA: Ce tile [16 x 128] ----
    f32x4 acc[8];
    #pragma unroll
    for (int ct = 0; ct < 8; ++ct) acc[ct] = (f32x4){0.f, 0.f, 0.f, 0.f};
    bf16x8 aF[4];
    #pragma unroll
    for (int ks = 0; ks < 4; ++ks)
        aF[ks] = ld8b(&Ebase[(size_t)(j0 + lr) * HD + ks * 32 + lg * 8]);
    #pragma unroll
    for (int ks = 0; ks < 4; ++ks)
        #pragma unroll
        for (int ct = 0; ct < 8; ++ct)
            acc[ct] = __builtin_amdgcn_mfma_f32_16x16x32_bf16(aF[ks], Bf[ct][ks], acc[ct], 0, 0, 0);

    __syncthreads();   // covers sAhC/sGe/sBe producer too

    // ---- dump D-layout acc to per-wave LDS tile (row = lg*4+r, col = ct*16+lr) ----
    #pragma unroll
    for (int ct = 0; ct < 8; ++ct)
        #pragma unroll
        for (int r = 0; r < 4; ++r)
            sm.sE[w][lg * 4 + r][ct * 16 + lr] = acc[ct][r];

    asm volatile("" ::: "memory");
    __builtin_amdgcn_wave_barrier();

    // ---- e_upd = Ce + AhC + Bh; LN stats ----
    const int j = j0 + row;
    float sum = 0.f, ssq = 0.f;
    #pragma unroll
    for (int c8 = 0; c8 < 8; ++c8) {
        f32x4 ev = *(f32x4*)&sm.sE[w][row][h0 + c8 * 4];
        f32x4 av = *(const f32x4*)&sm.sAhC[h0 + c8 * 4];
        f32x4 bv = *(const f32x4*)&BhB[(size_t)j * HD + h0 + c8 * 4];
        ev = ev + av + bv;
        #pragma unroll
        for (int e = 0; e < 4; ++e) { sum += ev[e]; ssq = fmaf(ev[e], ev[e], ssq); }
        *(f32x4*)&sm.sE[w][row][h0 + c8 * 4] = ev;
    }
    sum += __shfl_xor(sum, 1); ssq += __shfl_xor(ssq, 1);
    sum += __shfl_xor(sum, 2); ssq += __shfl_xor(ssq, 2);
    const float mean = sum * (1.f / HD);
    const float var  = ssq * (1.f / HD) - mean * mean;
    const float rstd = rsqrtf(var + 1e-5f);
    const float mk   = (float)adj[(size_t)bi * NN + j];

    // ---- sigmoid gates, masked agg, LN-apply + relu + residual ----
    float agg[32];
    #pragma unroll
    for (int c4 = 0; c4 < 4; ++c4) {
        const int hh = h0 + c4 * 8;
        f32x4 e0 = *(f32x4*)&sm.sE[w][row][hh];
        f32x4 e1 = *(f32x4*)&sm.sE[w][row][hh + 4];
        f32x4 v0 = *(const f32x4*)&VhB[(size_t)j * HD + hh];
        f32x4 v1 = *(const f32x4*)&VhB[(size_t)j * HD + hh + 4];
        float r8[8];
        ld8(&Ebase[(size_t)j * HD + hh], r8);
        f32x4 o0, o1;
        #pragma unroll
        for (int e = 0; e < 8; ++e) {
            const float ee = (e < 4) ? e0[e] : e1[e - 4];
            const float vv = (e < 4) ? v0[e] : v1[e - 4];
            const float g = 1.f / (1.f + exp2f(ee * -1.44269504f));
            agg[c4 * 8 + e] = g * mk * vv;
            float a = (ee - mean) * rstd;
            a = fmaf(a, sm.sGe[hh + e], sm.sBe[hh + e]);
            a = fmaxf(a, 0.f);
            if (e < 4) o0[e] = r8[e] + a; else o1[e - 4] = r8[e] + a;
        }
        *(f32x4*)&Obase[(size_t)j * HD + hh]     = o0;
        *(f32x4*)&Obase[(size_t)j * HD + hh + 4] = o1;
    }

    // ---- reduce agg over rows (lanes sharing l&3 hold same h-columns) ----
    #pragma unroll
    for (int k = 0; k < 32; ++k) {
        float v = agg[k];
        v += __shfl_xor(v, 4);
        v += __shfl_xor(v, 8);
        v += __shfl_xor(v, 16);
        v += __shfl_xor(v, 32);
        agg[k] = v;
    }
    if (row == 0) {
        #pragma unroll
        for (int k = 0; k < 32; ++k) sm.sAgg[w][c * 32 + k] = agg[k];
    }
    __syncthreads();

    // ---- per-block partial agg -> wagg ----
    if (t < HD) {
        float p = sm.sAgg[0][t] + sm.sAgg[1][t] + sm.sAgg[2][t] + sm.sAgg[3][t];
        wagg[((size_t)jc * ROWS + bi) * HD + t] = p;
    }
}

__global__ __launch_bounds__(256) void edge_kernel(
    const void* h_edges, const void* adj, const void* Cw,
    const void* ge, const void* be,
    float* __restrict__ ws, float* __restrict__ out)
{
    __shared__ Smem sm;
    float* wagg = ws + 4 * SZ;
    if (detect_f32(h_edges))
        edge_body<float>(sm, (const float*)h_edges, (const float*)adj, (const float*)Cw,
                         (const float*)ge, (const float*)be, ws, wagg, out);
    else
        edge_body<bf16_t>(sm, (const bf16_t*)h_edges, (const bf16_t*)adj, (const bf16_t*)Cw,
                          (const bf16_t*)ge, (const bf16_t*)be, ws, wagg, out);
}

// ---------------- Kernel 3: node update ----------------
// grid 768; block 64 (one wave, 2 cols/lane)
template<typename T>
__device__ void node_upd_body(const T* h_nodes, const T* gh, const T* bh,
                              const float* ws, float* out)
{
    const int bi = blockIdx.x, t = threadIdx.x;
    float x0 = ws[3 * SZ + bi * HD + t];
    float x1 = ws[3 * SZ + bi * HD + t + 64];
    #pragma unroll
    for (int jc = 0; jc < JC; ++jc) {
        const float* p = ws + 4 * SZ + ((size_t)jc * ROWS + bi) * HD;
        x0 += p[t];
        x1 += p[t + 64];
    }
    float sum = x0 + x1;
    float ssq = x0 * x0 + x1 * x1;
    #pragma unroll
    for (int off = 1; off < 64; off <<= 1) {
        sum += __shfl_xor(sum, off);
        ssq += __shfl_xor(ssq, off);
    }
    const float mean = sum * (1.f / HD);
    const float rstd = rsqrtf(ssq * (1.f / HD) - mean * mean + 1e-5f);
    float a0 = fmaf((x0 - mean) * rstd, (float)gh[t],      (float)bh[t]);
    float a1 = fmaf((x1 - mean) * rstd, (float)gh[t + 64], (float)bh[t + 64]);
    a0 = fmaxf(a0, 0.f);
    a1 = fmaxf(a1, 0.f);
    out[bi * HD + t]      = (float)h_nodes[bi * HD + t]      + a0;
    out[bi * HD + t + 64] = (float)h_nodes[bi * HD + t + 64] + a1;
}

__global__ __launch_bounds__(64) void node_update(
    const void* h_nodes, const void* gh, const void* bh,
    const float* __restrict__ ws, float* __restrict__ out)
{
    if (detect_f32(h_nodes))
        node_upd_body<float>((const float*)h_nodes, (const float*)gh, (const float*)bh, ws, out);
    else
        node_upd_body<bf16_t>((const bf16_t*)h_nodes, (const bf16_t*)gh, (const bf16_t*)bh, ws, out);
}

extern "C" void kernel_launch(void* const* d_in, const int* in_sizes, int n_in,
                              void* d_out, int out_size, void* d_ws, size_t ws_size,
                              hipStream_t stream)
{
    float* ws = (float*)d_ws;
    float* out = (float*)d_out;

    node_linear<<<dim3(ROWS, 4), dim3(128), 0, stream>>>(
        d_in[0], d_in[3], d_in[4], d_in[5], d_in[6], d_in[7], d_in[8],
        d_in[9], d_in[10], d_in[12], ws);
    edge_kernel<<<dim3(NN, JC, 2), dim3(256), 0, stream>>>(
        d_in[1], d_in[2], d_in[11], d_in[15], d_in[16], ws, out);
    node_update<<<dim3(ROWS), dim3(64), 0, stream>>>(
        d_in[0], d_in[13], d_in[14], ws, out);
}

// Round 6
// 198.268 us; speedup vs baseline: 1.5110x; 1.5110x over previous
//
#include <hip/hip_runtime.h>
#include <hip/hip_bf16.h>

typedef __bf16 bf16_t;
typedef __bf16 bf16x8 __attribute__((ext_vector_type(8)));
typedef __bf16 bf16x4 __attribute__((ext_vector_type(4)));
typedef float f32x4 __attribute__((ext_vector_type(4)));

#define HD 128
#define NN 384
#define ROWS 768           // B*N
#define SZ 98304           // ROWS*HD
#define JC 3               // j-chunks per (b,i): each block covers 128 j, each wave 32 j
// ws f32 layout: [0..4*SZ) = AhC, Bh, Vh, Uh ; [4*SZ..7*SZ) = agg partials [JC][ROWS][HD];
// ws[7*SZ] = dtype flag (int)

// ---- runtime input-dtype detector: 1 if buffer holds f32, 0 if bf16 ----
__device__ inline int detect_f32(const void* p) {
    const unsigned short* u = (const unsigned short*)p;
    int bad = 0;
    #pragma unroll
    for (int k = 0; k < 128; ++k) {
        int e = (u[k] >> 7) & 0xFF;
        bad += (e < 110 || e > 135) ? 1 : 0;
    }
    return bad >= 16 ? 1 : 0;
}

__global__ __launch_bounds__(64) void detect_kernel(const void* p, float* ws) {
    if (threadIdx.x == 0)
        *(int*)((char*)ws + (size_t)7 * SZ * 4) = detect_f32(p);
}

__device__ inline int read_flag(const float* ws) {
    return *(const int*)((const char*)ws + (size_t)7 * SZ * 4);
}

// ---- dtype-generic load helpers ----
__device__ inline void ld8(const float* p, float* o) {
    f32x4 a = *(const f32x4*)p;
    f32x4 b = *(const f32x4*)(p + 4);
    o[0] = a[0]; o[1] = a[1]; o[2] = a[2]; o[3] = a[3];
    o[4] = b[0]; o[5] = b[1]; o[6] = b[2]; o[7] = b[3];
}
__device__ inline void ld8(const bf16_t* p, float* o) {
    bf16x8 v = *(const bf16x8*)p;
    #pragma unroll
    for (int e = 0; e < 8; ++e) o[e] = (float)v[e];
}
__device__ inline bf16x8 ld8b(const float* p) {
    f32x4 a = *(const f32x4*)p;
    f32x4 b = *(const f32x4*)(p + 4);
    bf16x8 v;
    #pragma unroll
    for (int e = 0; e < 4; ++e) { v[e] = (bf16_t)a[e]; v[e + 4] = (bf16_t)b[e]; }
    return v;
}
__device__ inline bf16x8 ld8b(const bf16_t* p) { return *(const bf16x8*)p; }
__device__ inline f32x4 ld4f(const float* p) { return *(const f32x4*)p; }
__device__ inline f32x4 ld4f(const bf16_t* p) {
    bf16x4 v = *(const bf16x4*)p;
    f32x4 o;
    #pragma unroll
    for (int e = 0; e < 4; ++e) o[e] = (float)v[e];
    return o;
}

// ---------------- Kernel 1: node linear layers ----------------
// grid (768, 4): row x matrix; block 128
template<typename T>
__device__ void node_body(float* x,
    const T* h_nodes, const T* Uw, const T* Ub, const T* Vw, const T* Vb,
    const T* Aw, const T* Ab, const T* Bw, const T* Bb, const T* Cb,
    float* ws)
{
    const int row = blockIdx.x, m = blockIdx.y, t = threadIdx.x;
    x[t] = (float)h_nodes[row * HD + t];
    __syncthreads();

    const T* Ws[4] = {Aw, Bw, Vw, Uw};
    float bias;
    if (m == 0)      bias = (float)Ab[t] + (float)Cb[t];
    else if (m == 1) bias = (float)Bb[t];
    else if (m == 2) bias = (float)Vb[t];
    else             bias = (float)Ub[t];

    float acc = bias;
    const T* W = Ws[m] + (size_t)t * HD;
    #pragma unroll
    for (int kk = 0; kk < 16; ++kk) {
        float w8[8];
        ld8(W + kk * 8, w8);
        #pragma unroll
        for (int e = 0; e < 8; ++e) acc = fmaf(x[kk * 8 + e], w8[e], acc);
    }
    ws[m * SZ + row * HD + t] = acc;
}

__global__ __launch_bounds__(128) void node_linear(
    const void* h_nodes, const void* Uw, const void* Ub, const void* Vw, const void* Vb,
    const void* Aw, const void* Ab, const void* Bw, const void* Bb, const void* Cb,
    float* __restrict__ ws)
{
    __shared__ __align__(16) float x[HD];
    if (read_flag(ws))
        node_body<float>(x, (const float*)h_nodes, (const float*)Uw, (const float*)Ub,
                         (const float*)Vw, (const float*)Vb, (const float*)Aw, (const float*)Ab,
                         (const float*)Bw, (const float*)Bb, (const float*)Cb, ws);
    else
        node_body<bf16_t>(x, (const bf16_t*)h_nodes, (const bf16_t*)Uw, (const bf16_t*)Ub,
                          (const bf16_t*)Vw, (const bf16_t*)Vb, (const bf16_t*)Aw, (const bf16_t*)Ab,
                          (const bf16_t*)Bw, (const bf16_t*)Bb, (const bf16_t*)Cb, ws);
}

// ---------------- Kernel 2: edge pipeline, swapped-operand MFMA ----------------
// grid (384, JC, 2); block 256 = 4 waves; wave covers 32 j-rows (two 16-j sub-tiles).
// D = Cw * E^T: lane holds j = j0 + (l&15); h = ct*16 + (l>>4)*4 + r  -> LN/agg in registers.
struct Smem {
    float sAhC[HD], sGe[HD], sBe[HD];
    float sAgg[4][HD];
};

template<typename T>
__device__ inline void edge_epilogue(
    const Smem& sm, f32x4* acc, f32x4* agg,
    float mk, const float* Bhrow, const float* Vhrow,
    const T* Erow, float* Orow, int hbase)
{
    float sum = 0.f, ssq = 0.f;
    #pragma unroll
    for (int ct = 0; ct < 8; ++ct) {
        f32x4 e = acc[ct];
        f32x4 av = *(const f32x4*)&sm.sAhC[ct * 16 + hbase];
        f32x4 bv = *(const f32x4*)&Bhrow[ct * 16 + hbase];
        e = e + av + bv;
        acc[ct] = e;
        #pragma unroll
        for (int r = 0; r < 4; ++r) { sum += e[r]; ssq = fmaf(e[r], e[r], ssq); }
    }
    sum += __shfl_xor(sum, 16); ssq += __shfl_xor(ssq, 16);
    sum += __shfl_xor(sum, 32); ssq += __shfl_xor(ssq, 32);
    const float mean = sum * (1.f / HD);
    const float rstd = rsqrtf(ssq * (1.f / HD) - mean * mean + 1e-5f);
    #pragma unroll
    for (int ct = 0; ct < 8; ++ct) {
        f32x4 vv = *(const f32x4*)&Vhrow[ct * 16 + hbase];
        f32x4 rr = ld4f(&Erow[ct * 16 + hbase]);
        f32x4 ge4 = *(const f32x4*)&sm.sGe[ct * 16 + hbase];
        f32x4 be4 = *(const f32x4*)&sm.sBe[ct * 16 + hbase];
        f32x4 o;
        #pragma unroll
        for (int r = 0; r < 4; ++r) {
            const float ee = acc[ct][r];
            const float g = 1.f / (1.f + exp2f(ee * -1.44269504f));
            agg[ct][r] = fmaf(g * mk, vv[r], agg[ct][r]);
            float a = (ee - mean) * rstd;
            a = fmaf(a, ge4[r], be4[r]);
            a = fmaxf(a, 0.f);
            o[r] = rr[r] + a;
        }
        *(f32x4*)&Orow[ct * 16 + hbase] = o;
    }
}

template<typename T>
__device__ void edge_body(Smem& sm,
    const T* h_edges, const T* adj, const T* Cw,
    const T* ge, const T* be,
    const float* ws, float* wagg, float* out)
{
    const int i = blockIdx.x, jc = blockIdx.y, b = blockIdx.z;
    const int bi = b * NN + i;
    const int t = threadIdx.x;
    const int l = t & 63, w = t >> 6;
    const int lr = l & 15, lg = l >> 4;
    const int hbase = lg * 4;

    if (t < HD) {
        sm.sAhC[t] = ws[0 * SZ + bi * HD + t];
        sm.sGe[t]  = (float)ge[t];
        sm.sBe[t]  = (float)be[t];
    }

    const T* Ebase = h_edges + (size_t)bi * NN * HD;
    const int j0 = jc * 128 + w * 32;

    // ---- K-loop: per ks, load Bf slice (8 ct) + 2 A-frags, issue 16 MFMA ----
    f32x4 acc0[8], acc1[8];
    #pragma unroll
    for (int ct = 0; ct < 8; ++ct) {
        acc0[ct] = (f32x4){0.f, 0.f, 0.f, 0.f};
        acc1[ct] = (f32x4){0.f, 0.f, 0.f, 0.f};
    }
    #pragma unroll 1
    for (int ks = 0; ks < 4; ++ks) {
        bf16x8 Bf[8];
        #pragma unroll
        for (int ct = 0; ct < 8; ++ct)
            Bf[ct] = ld8b(&Cw[(size_t)(ct * 16 + lr) * HD + ks * 32 + lg * 8]);
        bf16x8 a0 = ld8b(&Ebase[(size_t)(j0 + lr) * HD + ks * 32 + lg * 8]);
        bf16x8 a1 = ld8b(&Ebase[(size_t)(j0 + 16 + lr) * HD + ks * 32 + lg * 8]);
        #pragma unroll
        for (int ct = 0; ct < 8; ++ct)
            acc0[ct] = __builtin_amdgcn_mfma_f32_16x16x32_bf16(Bf[ct], a0, acc0[ct], 0, 0, 0);
        #pragma unroll
        for (int ct = 0; ct < 8; ++ct)
            acc1[ct] = __builtin_amdgcn_mfma_f32_16x16x32_bf16(Bf[ct], a1, acc1[ct], 0, 0, 0);
    }

    __syncthreads();   // sAhC/sGe/sBe ready (staged by t<128 above)

    const float* BhB = ws + 1 * SZ + (size_t)b * NN * HD;
    const float* VhB = ws + 2 * SZ + (size_t)b * NN * HD;
    float* Obase = out + SZ + (size_t)bi * NN * HD;

    f32x4 agg4[8];
    #pragma unroll
    for (int ct = 0; ct < 8; ++ct) agg4[ct] = (f32x4){0.f, 0.f, 0.f, 0.f};

    {
        const int j = j0 + lr;
        const float mk = (float)adj[(size_t)bi * NN + j];
        edge_epilogue(sm, acc0, agg4, mk, &BhB[(size_t)j * HD], &VhB[(size_t)j * HD],
                      &Ebase[(size_t)j * HD], &Obase[(size_t)j * HD], hbase);
    }
    {
        const int j = j0 + 16 + lr;
        const float mk = (float)adj[(size_t)bi * NN + j];
        edge_epilogue(sm, acc1, agg4, mk, &BhB[(size_t)j * HD], &VhB[(size_t)j * HD],
                      &Ebase[(size_t)j * HD], &Obase[(size_t)j * HD], hbase);
    }

    // ---- reduce agg over j (lr lanes) ----
    #pragma unroll
    for (int ct = 0; ct < 8; ++ct)
        #pragma unroll
        for (int r = 0; r < 4; ++r) {
            float v = agg4[ct][r];
            v += __shfl_xor(v, 1);
            v += __shfl_xor(v, 2);
            v += __shfl_xor(v, 4);
            v += __shfl_xor(v, 8);
            agg4[ct][r] = v;
        }
    if (lr == 0) {
        #pragma unroll
        for (int ct = 0; ct < 8; ++ct)
            *(f32x4*)&sm.sAgg[w][ct * 16 + hbase] = agg4[ct];
    }
    __syncthreads();

    if (t < HD) {
        float p = sm.sAgg[0][t] + sm.sAgg[1][t] + sm.sAgg[2][t] + sm.sAgg[3][t];
        wagg[((size_t)jc * ROWS + bi) * HD + t] = p;
    }
}

__global__ __launch_bounds__(256, 3) void edge_kernel(
    const void* h_edges, const void* adj, const void* Cw,
    const void* ge, const void* be,
    float* __restrict__ ws, float* __restrict__ out)
{
    __shared__ Smem sm;
    float* wagg = ws + 4 * SZ;
    if (read_flag(ws))
        edge_body<float>(sm, (const float*)h_edges, (const float*)adj, (const float*)Cw,
                         (const float*)ge, (const float*)be, ws, wagg, out);
    else
        edge_body<bf16_t>(sm, (const bf16_t*)h_edges, (const bf16_t*)adj, (const bf16_t*)Cw,
                          (const bf16_t*)ge, (const bf16_t*)be, ws, wagg, out);
}

// ---------------- Kernel 3: node update ----------------
// grid 768; block 64 (one wave, 2 cols/lane)
template<typename T>
__device__ void node_upd_body(const T* h_nodes, const T* gh, const T* bh,
                              const float* ws, float* out)
{
    const int bi = blockIdx.x, t = threadIdx.x;
    float x0 = ws[3 * SZ + bi * HD + t];
    float x1 = ws[3 * SZ + bi * HD + t + 64];
    #pragma unroll
    for (int jc = 0; jc < JC; ++jc) {
        const float* p = ws + 4 * SZ + ((size_t)jc * ROWS + bi) * HD;
        x0 += p[t];
        x1 += p[t + 64];
    }
    float sum = x0 + x1;
    float ssq = x0 * x0 + x1 * x1;
    #pragma unroll
    for (int off = 1; off < 64; off <<= 1) {
        sum += __shfl_xor(sum, off);
        ssq += __shfl_xor(ssq, off);
    }
    const float mean = sum * (1.f / HD);
    const float rstd = rsqrtf(ssq * (1.f / HD) - mean * mean + 1e-5f);
    float a0 = fmaf((x0 - mean) * rstd, (float)gh[t],      (float)bh[t]);
    float a1 = fmaf((x1 - mean) * rstd, (float)gh[t + 64], (float)bh[t + 64]);
    a0 = fmaxf(a0, 0.f);
    a1 = fmaxf(a1, 0.f);
    out[bi * HD + t]      = (float)h_nodes[bi * HD + t]      + a0;
    out[bi * HD + t + 64] = (float)h_nodes[bi * HD + t + 64] + a1;
}

__global__ __launch_bounds__(64) void node_update(
    const void* h_nodes, const void* gh, const void* bh,
    const float* __restrict__ ws, float* __restrict__ out)
{
    if (read_flag(ws))
        node_upd_body<float>((const float*)h_nodes, (const float*)gh, (const float*)bh, ws, out);
    else
        node_upd_body<bf16_t>((const bf16_t*)h_nodes, (const bf16_t*)gh, (const bf16_t*)bh, ws, out);
}

extern "C" void kernel_launch(void* const* d_in, const int* in_sizes, int n_in,
                              void* d_out, int out_size, void* d_ws, size_t ws_size,
                              hipStream_t stream)
{
    float* ws = (float*)d_ws;
    float* out = (float*)d_out;

    detect_kernel<<<dim3(1), dim3(64), 0, stream>>>(d_in[0], ws);
    node_linear<<<dim3(ROWS, 4), dim3(128), 0, stream>>>(
        d_in[0], d_in[3], d_in[4], d_in[5], d_in[6], d_in[7], d_in[8],
        d_in[9], d_in[10], d_in[12], ws);
    edge_kernel<<<dim3(NN, JC, 2), dim3(256), 0, stream>>>(
        d_in[1], d_in[2], d_in[11], d_in[15], d_in[16], ws, out);
    node_update<<<dim3(ROWS), dim3(64), 0, stream>>>(
        d_in[0], d_in[13], d_in[14], ws, out);
}